// Round 1
// baseline (361.647 us; speedup 1.0000x reference)
//
#include <hip/hip_runtime.h>
#include <hip/hip_cooperative_groups.h>
#include <hip/hip_fp16.h>
#include <math.h>
#include <type_traits>

namespace cg = cooperative_groups;

// ----------------------------------------------------------------------------
// NL-means denoise (skimage slow-mode math) + db2-wavelet sigma estimate.
// R14: FUSED single cooperative kernel. Rationale: steady-state nlm_main is
//   ~165us but the bench measures 228.8us -- the ~64us gap is the serialized
//   prologue (memset -> wavelet_hist at 66K threads / latency-bound ->
//   sigma_scan at 3 blocks -> 3 launch bubbles). Fuse:
//     phase H: 198147 per-channel HH-conv+hist items over all 262144 threads
//              (overlapped with each block's spx tile load)
//     grid.sync -> blocks 0..2: median scan (scratch aliased onto sds)
//     grid.sync -> sigma = sum(med_c)*MAD_INV/3, then unchanged R13 main loop.
//   Grid 512 blocks x 512 thr = exactly 2 blocks/CU x 256 CU (LDS 73.4KB),
//   launched via hipLaunchCooperativeKernel (harness-supported); old 3-kernel
//   path kept as fallback if the cooperative launch errors.
// R13: swt own buffer -> 3 barriers/iter, C overlaps next A. (unchanged)
// ----------------------------------------------------------------------------

#define IMG   1024
#define HH_S  257
#define NBINS 4096
#define NREP  2
#define BIN_SCALE 4096.0f
#define MED_K 33025      // n=257*257=66049 odd: median = a[33024] (0-based)

#define TW 64
#define TH 32
// spx: rows -8..39 (48) x cols -14..77 (92)
#define PROWS 48
#define PCOLS 92
#define NPIX (PROWS*PCOLS)           // 4416
#define PXB(r,c) (((r)+8)*PCOLS + ((c)+14))
// sd: rows -8..33 (42) x cols -8..71 (80)
#define DCOLS 80
#define ND 3360                      // 42*80
// sh: rows -8..33 (42) x cols -6..69 (76)
#define HCOLS 76
#define NH 3192                      // 42*76
// swt: rows -6..31 (38) x cols -6..69 (76) — separate buffer (R13)
#define NW 2888                      // 38*76
#define NWP 1444                     // 38 rows x 38 col-pairs
#define SWB(r,c) (((r)+6)*HCOLS + ((c)+6))

// Gaussian patch kernel, normalized separable taps
#define G0 0.05448868454910367f
#define G1 0.24420134203151178f
#define G2 0.40261994689466440f
// horizontal pass taps pre-multiplied by 1/3 (channel mean)
#define B0 0.01816289484970122f
#define B1 0.08140044734383726f
#define B2 0.13420664896488813f

#define MAD_INV 1.4826022185056018f
#define LOG2E   1.4426950408889634f

typedef _Float16 half2v __attribute__((ext_vector_type(2)));
union PxU { uint2 u; half2v h[2]; };
union Q4  { uint4 u; half2v h[4]; };
union Q2  { uint2 u; half2v h[2]; };
#define H2(x) half2v{(_Float16)(x), (_Float16)(x)}

// ---------------------------------------------------------------- helpers
__device__ __forceinline__ float diff2(half2v a01, half2v a2, half2v b01, half2v b2) {
#if __has_builtin(__builtin_amdgcn_fdot2)
    half2v e01 = a01 - b01;
    half2v e2  = a2  - b2;
    return __builtin_amdgcn_fdot2(e01, e01,
           __builtin_amdgcn_fdot2(e2, e2, 0.f, false), false);
#else
    float e0 = (float)a01[0] - (float)b01[0];
    float e1 = (float)a01[1] - (float)b01[1];
    float e2 = (float)a2[0]  - (float)b2[0];
    return e0 * e0 + e1 * e1 + e2 * e2;
#endif
}

__device__ __forceinline__ half2v pack2(float a, float b) {
#if __has_builtin(__builtin_amdgcn_cvt_pkrtz)
    return __builtin_bit_cast(half2v, __builtin_amdgcn_cvt_pkrtz(a, b));
#else
    return half2v{(_Float16)a, (_Float16)b};
#endif
}

// load reflect-padded pixel tile, pack RGB -> 3xfp16 in uint2
__device__ __forceinline__ void tile_load(const float* __restrict__ x, uint2* spx,
                                          int tid, int X0, int Y0) {
    for (int l = tid; l < NPIX; l += 512) {
        int rr = l / PCOLS;
        int cc = l - rr * PCOLS;
        int sy = Y0 + rr - 8;
        sy = sy < 0 ? -sy : (sy >= IMG ? 2 * IMG - 2 - sy : sy);
        int sc = X0 + cc - 14;
        sc = sc < 0 ? -sc : (sc >= IMG ? 2 * IMG - 2 - sc : sc);
        const float* p = x + ((size_t)sy * IMG + sc) * 3;
        uint2 u;
        u.x = (unsigned)__half_as_ushort(__float2half_rn(p[0])) |
              ((unsigned)__half_as_ushort(__float2half_rn(p[1])) << 16);
        u.y = (unsigned)__half_as_ushort(__float2half_rn(p[2]));  // hi 16 = 0
        spx[l] = u;
    }
}

// one HH coefficient for one channel -> histogram atomic (stride-2 SAMPLED grid)
__device__ __forceinline__ void hist_accum(const float* __restrict__ x,
                                           int* __restrict__ hist,
                                           int gtid, int rep) {
    if (gtid >= HH_S * HH_S * 3) return;
    int idx = gtid / 3;
    int c   = gtid - idx * 3;
    int i = idx / HH_S;
    int j = idx - i * HH_S;
    const float k4[4] = {-0.48296291314469025f, 0.8365163037378079f,
                         -0.2241438680420134f, -0.12940952255126037f};
    float acc = 0.f;
    const bool fast = (j >= 2);          // j <= 256 so upper bound always ok
#pragma unroll
    for (int a = 0; a < 4; ++a) {
        int sy = 2 * i + a - 3;                       // 'symmetric' pad
        sy = sy < 0 ? -sy - 1 : (sy >= IMG ? 2 * IMG - 1 - sy : sy);
        const float* row = x + (size_t)sy * IMG * 3;
        float r;
        if (fast) {
            const float* p = row + (2 * j - 3) * 3 + c;
            r = k4[0] * p[0] + k4[1] * p[3] + k4[2] * p[6] + k4[3] * p[9];
        } else {
            r = 0.f;
#pragma unroll
            for (int b = 0; b < 4; ++b) {
                int sx = 2 * j + b - 3;
                sx = sx < 0 ? -sx - 1 : sx;
                r += k4[b] * row[sx * 3 + c];
            }
        }
        acc += k4[a] * r;
    }
    int b0 = (int)(fabsf(acc) * BIN_SCALE); b0 = b0 > NBINS - 1 ? NBINS - 1 : b0;
    atomicAdd(&hist[rep * 3 * NBINS + c * NBINS + b0], 1);
}

// block-level histogram median for channel c (512 threads x 8 bins);
// wsum: 8-int scratch (aliased onto sds -- used before sds's first write)
__device__ __forceinline__ void median_scan(const int* __restrict__ hist,
                                            float* __restrict__ scal,
                                            int c, int tid, int* wsum) {
    const int lane = tid & 63, wid = tid >> 6;
    const int* h = hist + c * NBINS;
    int cnt[8]; int tsum = 0;
#pragma unroll
    for (int b = 0; b < 8; ++b) {
        int bin = tid * 8 + b, s = 0;
#pragma unroll
        for (int r = 0; r < NREP; ++r) s += h[r * 3 * NBINS + bin];
        cnt[b] = s; tsum += s;
    }
    int incl = tsum;
#pragma unroll
    for (int o = 1; o < 64; o <<= 1) {
        int v = __shfl_up(incl, o);
        if (lane >= o) incl += v;
    }
    if (lane == 63) wsum[wid] = incl;
    __syncthreads();
    if (wid == 0) {
        int v = (lane < 8) ? wsum[lane] : 0;
        int inc = v;
#pragma unroll
        for (int o = 1; o < 8; o <<= 1) {
            int u = __shfl_up(inc, o);
            if (lane >= o) inc += u;
        }
        if (lane < 8) wsum[lane] = inc - v;
    }
    __syncthreads();
    int cum = wsum[wid] + incl - tsum;
#pragma unroll
    for (int b = 0; b < 8; ++b) {
        int nc = cum + cnt[b];
        if (cum < MED_K && nc >= MED_K)
            scal[c] = (tid * 8 + b + 0.5f) * (1.0f / BIN_SCALE);   // raw median
        cum = nc;
    }
}

// ---------------------------------------------------------------- main loop
// Unchanged R13 body: 42 iters x (A: packed diff^2 -> sds, B: horiz 5-tap ->
// shh, W: vert 5-tap + exp2 -> swt, C: 4-direction accumulate). 3 barriers.
__device__ __forceinline__ void nlm_loop(float* __restrict__ out, float sigma,
                                         uint2* spx, half2v* sds, half2v* shh,
                                         half2v* swt, int tid, int X0, int Y0) {
    const float var   = 2.0f * sigma * sigma;
    const float ih2l  = LOG2E / (0.64f * sigma * sigma);   // h = 0.8*sigma

    const int c  = tid & 63;          // output col within tile
    const int rg = (tid >> 6) * 4;    // first of 4 output rows (0..28)
    float accx[4] = {0, 0, 0, 0}, accy[4] = {0, 0, 0, 0};
    float accz[4] = {0, 0, 0, 0}, accw[4] = {0, 0, 0, 0};

    __syncthreads();

    // --- register-cache center values + spx base index for phase A tasks
    half2v ctr01[7], ctr2[7];
    int    pb[7];
#pragma unroll
    for (int k = 0; k < 7; ++k) {
        int i = (k < 6 || tid < ND - 6 * 512) ? tid + k * 512 : 0;
        int dr = i / DCOLS;
        int dc = i - dr * DCOLS;
        pb[k] = dr * PCOLS + dc + 6;   // PXB(dr-8, dc-8)
        PxU p; p.u = spx[pb[k]];
        ctr01[k] = p.h[0]; ctr2[k] = p.h[1];
    }

    const half2v B0h = H2(B0), B1h = H2(B1), B2h = H2(B2);
    const half2v G0h = H2(G0), G1h = H2(G1), G2h = H2(G2);

    // ---- pair body: offsets o1=(oy1,ox1), o2=(oy2,ox2) packed as half2;
    // each serves BOTH +o and -o directions (dist_{-o}(p) = dist_o(p-o)).
    auto pair_body = [&](auto mtag, int oy1, int ox1, int oy2, int ox2) {
        constexpr bool MERGED = decltype(mtag)::value;
        const int d1off = oy1 * PCOLS + ox1;
        const int d2off = oy2 * PCOLS + ox2;

        // -------- phase A: packed diff^2 on 42x80 ext region -> sds
#pragma unroll
        for (int k = 0; k < 7; ++k) {
            if (k < 6 || tid < ND - 6 * 512) {
                PxU p1, p2;
                p1.u = spx[pb[k] + d1off];
                if constexpr (MERGED) p2.u = spx[pb[k] + d1off + 1];
                else                  p2.u = spx[pb[k] + d2off];
                float da = diff2(ctr01[k], ctr2[k], p1.h[0], p1.h[1]);
                float db = diff2(ctr01[k], ctr2[k], p2.h[0], p2.h[1]);
                sds[tid + k * 512] = pack2(da, db);
            }
        }
        __syncthreads();

        // -------- phase B: packed horizontal conv -> shh (798 b128 tasks)
        {
            int row = tid / 19, g = tid - row * 19;
            int b = row * DCOLS + 4 * g;
            Q4 a, q, o;
            a.u = *(const uint4*)&sds[b];
            q.u = *(const uint4*)&sds[b + 4];
            o.h[0] = B0h * a.h[0] + B1h * a.h[1] + B2h * a.h[2] + B1h * a.h[3] + B0h * q.h[0];
            o.h[1] = B0h * a.h[1] + B1h * a.h[2] + B2h * a.h[3] + B1h * q.h[0] + B0h * q.h[1];
            o.h[2] = B0h * a.h[2] + B1h * a.h[3] + B2h * q.h[0] + B1h * q.h[1] + B0h * q.h[2];
            o.h[3] = B0h * a.h[3] + B1h * q.h[0] + B2h * q.h[1] + B1h * q.h[2] + B0h * q.h[3];
            *(uint4*)&shh[row * HCOLS + 4 * g] = o.u;
            if (tid < 798 - 512) {
                int j2 = tid + 512;
                int row2 = j2 / 19, g2 = j2 - row2 * 19;
                int b2 = row2 * DCOLS + 4 * g2;
                a.u = *(const uint4*)&sds[b2];
                q.u = *(const uint4*)&sds[b2 + 4];
                o.h[0] = B0h * a.h[0] + B1h * a.h[1] + B2h * a.h[2] + B1h * a.h[3] + B0h * q.h[0];
                o.h[1] = B0h * a.h[1] + B1h * a.h[2] + B2h * a.h[3] + B1h * q.h[0] + B0h * q.h[1];
                o.h[2] = B0h * a.h[2] + B1h * a.h[3] + B2h * q.h[0] + B1h * q.h[1] + B0h * q.h[2];
                o.h[3] = B0h * a.h[3] + B1h * q.h[0] + B2h * q.h[1] + B1h * q.h[2] + B0h * q.h[3];
                *(uint4*)&shh[row2 * HCOLS + 4 * g2] = o.u;
            }
        }
        __syncthreads();

        // -------- phase W: vert conv + exp2 weights, column-pair b64 tasks
#pragma unroll
        for (int k = 0; k < 3; ++k) {
            int t = tid + k * 512;
            if (k < 2 || t < NWP) {
                int row = t / 38, cp = t - row * 38;
                int m = row * HCOLS + 2 * cp;
                Q2 s0, s1, s2, s3, s4, o;
                s0.u = *(const uint2*)&shh[m];
                s1.u = *(const uint2*)&shh[m + HCOLS];
                s2.u = *(const uint2*)&shh[m + 2 * HCOLS];
                s3.u = *(const uint2*)&shh[m + 3 * HCOLS];
                s4.u = *(const uint2*)&shh[m + 4 * HCOLS];
                half2v d0 = G0h * s0.h[0] + G1h * s1.h[0] + G2h * s2.h[0] + G1h * s3.h[0] + G0h * s4.h[0];
                half2v d1 = G0h * s0.h[1] + G1h * s1.h[1] + G2h * s2.h[1] + G1h * s3.h[1] + G0h * s4.h[1];
                o.h[0] = pack2(exp2f(fminf(var - (float)d0[0], 0.f) * ih2l),
                               exp2f(fminf(var - (float)d0[1], 0.f) * ih2l));
                o.h[1] = pack2(exp2f(fminf(var - (float)d1[0], 0.f) * ih2l),
                               exp2f(fminf(var - (float)d1[1], 0.f) * ih2l));
                *(uint2*)&swt[m] = o.u;
            }
        }
        __syncthreads();

        // -------- phase C: accumulate 4 directions per packed pair
        // (overlaps with next iteration's phase A — no trailing barrier)
#pragma unroll
        for (int j = 0; j < 4; ++j) {
            int r = rg + j;
            half2v wp = swt[SWB(r, c)];
            _Float16 wm1h, wm2h;
            PxU pa, pbx, pm1, pm2;
            if constexpr (MERGED) {
                int wmb = SWB(r - oy1, c - ox1);
                wm1h = swt[wmb][0];
                wm2h = swt[wmb - 1][1];
                int ab = PXB(r + oy1, c + ox1);
                pa.u  = spx[ab]; pbx.u = spx[ab + 1];
                int mb = PXB(r - oy1, c - ox1);
                pm1.u = spx[mb]; pm2.u = spx[mb - 1];
            } else {
                wm1h  = swt[SWB(r - oy1, c - ox1)][0];
                wm2h  = swt[SWB(r - oy2, c - ox2)][1];
                pa.u  = spx[PXB(r + oy1, c + ox1)];
                pbx.u = spx[PXB(r + oy2, c + ox2)];
                pm1.u = spx[PXB(r - oy1, c - ox1)];
                pm2.u = spx[PXB(r - oy2, c - ox2)];
            }
            float w1 = (float)wp[0], w2 = (float)wp[1];
            float f1 = (float)wm1h, f2 = (float)wm2h;
            accx[j] += w1 * (float)pa.h[0][0] + w2 * (float)pbx.h[0][0]
                     + f1 * (float)pm1.h[0][0] + f2 * (float)pm2.h[0][0];
            accy[j] += w1 * (float)pa.h[0][1] + w2 * (float)pbx.h[0][1]
                     + f1 * (float)pm1.h[0][1] + f2 * (float)pm2.h[0][1];
            accz[j] += w1 * (float)pa.h[1][0] + w2 * (float)pbx.h[1][0]
                     + f1 * (float)pm1.h[1][0] + f2 * (float)pm2.h[1][0];
            accw[j] += (w1 + w2) + (f1 + f2);
        }
    };

    // ---- 42 iterations cover 84 representative offsets x 2 directions:
    // oy=0: ox 1..6 as merged pairs (1,2),(3,4),(5,6)
#pragma unroll 1
    for (int pi = 0; pi < 3; ++pi)
        pair_body(std::integral_constant<bool, true>{}, 0, 1 + 2 * pi, 0, 2 + 2 * pi);
    // oy=1..6: ox -6..5 as 6 merged pairs per row
#pragma unroll 1
    for (int oy = 1; oy <= 6; ++oy)
#pragma unroll 1
        for (int pi = 0; pi < 6; ++pi)
            pair_body(std::integral_constant<bool, true>{}, oy, -6 + 2 * pi, oy, -5 + 2 * pi);
    // leftovers (oy,6) for oy=1..6 as 3 generic pairs
#pragma unroll 1
    for (int p = 0; p < 3; ++p)
        pair_body(std::integral_constant<bool, false>{}, 2 * p + 1, 6, 2 * p + 2, 6);

    // -------- offset (0,0): d=0 -> w=1
#pragma unroll
    for (int j = 0; j < 4; ++j) {
        PxU p; p.u = spx[PXB(rg + j, c)];
        accx[j] += (float)p.h[0][0];
        accy[j] += (float)p.h[0][1];
        accz[j] += (float)p.h[1][0];
        accw[j] += 1.f;
    }

    // -------- epilogue
#pragma unroll
    for (int j = 0; j < 4; ++j) {
        int po = ((Y0 + rg + j) * IMG + X0 + c) * 3;
        float rw = 1.f / accw[j];
        out[po + 0] = accx[j] * rw;
        out[po + 1] = accy[j] * rw;
        out[po + 2] = accz[j] * rw;
    }
}

// ---------------------------------------------------------------- fused kernel
__launch_bounds__(512, 4)
__global__ void nlm_fused(const float* __restrict__ x, float* __restrict__ scal,
                          int* __restrict__ hist, float* __restrict__ out) {
    __shared__ __align__(16) uint2  spx[NPIX];   // packed half RGB (RO in loop)
    __shared__ __align__(16) half2v sds[ND];     // diff^2 pairs
    __shared__ __align__(16) half2v shh[NH];     // horiz-conv pairs
    __shared__ __align__(16) half2v swt[NW];     // weight pairs

    const int tid = threadIdx.x;
    const int bid = blockIdx.y * gridDim.x + blockIdx.x;
    const int X0 = blockIdx.x * TW;
    const int Y0 = blockIdx.y * TH;

    // phase H: one per-channel HH coefficient per thread (198147 items over
    // 262144 threads), overlapped with this block's own tile load
    hist_accum(x, hist, bid * 512 + tid, bid & (NREP - 1));
    tile_load(x, spx, tid, X0, Y0);

    cg::this_grid().sync();

    // blocks 0..2: per-channel median scan (scratch aliased onto sds)
    if (bid < 3) median_scan(hist, scal, bid, tid, (int*)sds);

    cg::this_grid().sync();

    float s0 = __hip_atomic_load(&scal[0], __ATOMIC_RELAXED, __HIP_MEMORY_SCOPE_AGENT);
    float s1 = __hip_atomic_load(&scal[1], __ATOMIC_RELAXED, __HIP_MEMORY_SCOPE_AGENT);
    float s2 = __hip_atomic_load(&scal[2], __ATOMIC_RELAXED, __HIP_MEMORY_SCOPE_AGENT);
    const float sigma = (s0 + s1 + s2) * (MAD_INV / 3.0f);

    nlm_loop(out, sigma, spx, sds, shh, swt, tid, X0, Y0);
}

// ---------------------------------------------------------------- fallback path
// (old 3-kernel pipeline, used only if hipLaunchCooperativeKernel errors)
__global__ void wavelet_hist(const float* __restrict__ x, int* __restrict__ hist) {
    int idx = blockIdx.x * 256 + threadIdx.x;
    if (idx >= HH_S * HH_S) return;
    int* hrep = hist + (blockIdx.x & (NREP - 1)) * 3 * NBINS;
    int i = (idx / HH_S) * 2;
    int j = (idx - (idx / HH_S) * HH_S) * 2;
    const float k4[4] = {-0.48296291314469025f, 0.8365163037378079f,
                         -0.2241438680420134f, -0.12940952255126037f};
    float acc0 = 0.f, acc1 = 0.f, acc2 = 0.f;
    const bool fast = (j >= 2 && j <= 511);
#pragma unroll
    for (int a = 0; a < 4; ++a) {
        int sy = 2 * i + a - 3;                       // 'symmetric' pad
        sy = sy < 0 ? -sy - 1 : (sy >= IMG ? 2 * IMG - 1 - sy : sy);
        const float* row = x + (size_t)sy * IMG * 3;
        float r0, r1, r2;
        if (fast) {
            const float* p = row + (2 * j - 3) * 3;
            float f0 = p[0], f1 = p[1], f2 = p[2], f3 = p[3];
            float f4 = p[4], f5 = p[5], f6 = p[6], f7 = p[7];
            float f8 = p[8], f9 = p[9], f10 = p[10], f11 = p[11];
            r0 = k4[0] * f0 + k4[1] * f3 + k4[2] * f6 + k4[3] * f9;
            r1 = k4[0] * f1 + k4[1] * f4 + k4[2] * f7 + k4[3] * f10;
            r2 = k4[0] * f2 + k4[1] * f5 + k4[2] * f8 + k4[3] * f11;
        } else {
            r0 = r1 = r2 = 0.f;
#pragma unroll
            for (int b = 0; b < 4; ++b) {
                int sx = 2 * j + b - 3;
                sx = sx < 0 ? -sx - 1 : (sx >= IMG ? 2 * IMG - 1 - sx : sx);
                const float* p = row + sx * 3;
                r0 += k4[b] * p[0]; r1 += k4[b] * p[1]; r2 += k4[b] * p[2];
            }
        }
        acc0 += k4[a] * r0; acc1 += k4[a] * r1; acc2 += k4[a] * r2;
    }
    int b0 = (int)(fabsf(acc0) * BIN_SCALE); b0 = b0 > NBINS - 1 ? NBINS - 1 : b0;
    int b1 = (int)(fabsf(acc1) * BIN_SCALE); b1 = b1 > NBINS - 1 ? NBINS - 1 : b1;
    int b2 = (int)(fabsf(acc2) * BIN_SCALE); b2 = b2 > NBINS - 1 ? NBINS - 1 : b2;
    atomicAdd(&hrep[b0], 1);
    atomicAdd(&hrep[NBINS + b1], 1);
    atomicAdd(&hrep[2 * NBINS + b2], 1);
}

__global__ void sigma_scan(const int* __restrict__ hist, float* __restrict__ scal) {
    __shared__ int   wsum[16];
    __shared__ float sres[1];
    const int t = threadIdx.x;
    const int lane = t & 63, wid = t >> 6;
    const int c = blockIdx.x;
    const int* h = hist + c * NBINS;
    int cnt[4]; int tsum = 0;
#pragma unroll
    for (int b = 0; b < 4; ++b) {
        int bin = t * 4 + b, s = 0;
#pragma unroll
        for (int r = 0; r < NREP; ++r) s += h[r * 3 * NBINS + bin];
        cnt[b] = s; tsum += s;
    }
    int incl = tsum;
#pragma unroll
    for (int o = 1; o < 64; o <<= 1) {
        int v = __shfl_up(incl, o);
        if (lane >= o) incl += v;
    }
    if (lane == 63) wsum[wid] = incl;
    __syncthreads();
    if (wid == 0) {
        int v = (lane < 16) ? wsum[lane] : 0;
        int inc = v;
#pragma unroll
        for (int o = 1; o < 16; o <<= 1) {
            int u = __shfl_up(inc, o);
            if (lane >= o) inc += u;
        }
        if (lane < 16) wsum[lane] = inc - v;
    }
    __syncthreads();
    int cum = wsum[wid] + incl - tsum;
#pragma unroll
    for (int b = 0; b < 4; ++b) {
        int nc = cum + cnt[b];
        float v = (t * 4 + b + 0.5f) * (1.0f / BIN_SCALE);
        if (cum < MED_K && nc >= MED_K) sres[0] = v;
        cum = nc;
    }
    __syncthreads();
    if (t == 0) atomicAdd(&scal[0], sres[0] * (MAD_INV / 3.0f));
}

__launch_bounds__(512, 4)
__global__ void nlm_main(const float* __restrict__ x,
                         const float* __restrict__ scal,
                         float* __restrict__ out) {
    __shared__ __align__(16) uint2  spx[NPIX];
    __shared__ __align__(16) half2v sds[ND];
    __shared__ __align__(16) half2v shh[NH];
    __shared__ __align__(16) half2v swt[NW];

    const int tid = threadIdx.x;
    const int X0 = blockIdx.x * TW;
    const int Y0 = blockIdx.y * TH;

    tile_load(x, spx, tid, X0, Y0);
    const float sigma = scal[0];
    nlm_loop(out, sigma, spx, sds, shh, swt, tid, X0, Y0);
}

// ---------------------------------------------------------------- launch
extern "C" void kernel_launch(void* const* d_in, const int* in_sizes, int n_in,
                              void* d_out, int out_size, void* d_ws, size_t ws_size,
                              hipStream_t stream) {
    const float* x = (const float*)d_in[0];
    float* out = (float*)d_out;
    float* scal = (float*)d_ws;                       // [0..2] = per-ch medians
    int* hist = (int*)((char*)d_ws + 64);             // NREP x 3 x 4096 ints

    // zero scal + histograms in one memset
    (void)hipMemsetAsync(d_ws, 0, 64 + NREP * 3 * NBINS * sizeof(int), stream);

    dim3 grid(IMG / TW, IMG / TH);                    // 16 x 32 = 512 blocks
    const float* xa = x; float* sa = scal; int* ha = hist; float* oa = out;
    void* args[] = {(void*)&xa, (void*)&sa, (void*)&ha, (void*)&oa};
    hipError_t e = hipLaunchCooperativeKernel((const void*)nlm_fused, grid,
                                              dim3(512, 1, 1), args, 0, stream);
    if (e != hipSuccess) {
        // fallback: old serialized 3-kernel pipeline (scal[0] = sigma accum)
        wavelet_hist<<<(HH_S * HH_S + 255) / 256, 256, 0, stream>>>(x, hist);
        sigma_scan<<<3, 1024, 0, stream>>>(hist, scal);
        nlm_main<<<grid, 512, 0, stream>>>(x, scal, out);
    }
}

// Round 2
// 265.369 us; speedup vs baseline: 1.3628x; 1.3628x over previous
//
#include <hip/hip_runtime.h>
#include <hip/hip_fp16.h>
#include <math.h>
#include <type_traits>

// ----------------------------------------------------------------------------
// NL-means denoise (skimage slow-mode math) + db2-wavelet sigma estimate.
// R15: cooperative fusion REVERTED (R14 post-mortem: grid.sync cost ~136us --
//   main loop itself ran at the old speed, VALUBusy 38.8%x301us == 72%x165us).
//   Instead:
//   (a) hist+median fused into ONE kernel via __threadfence + atomic-counter
//       last-block pattern (no grid-wide sync; only the last block scans).
//       3x hist TLP: one per-channel item per thread (198K thr, 194x1024).
//       Dispatches 4 -> 3 (memset, hist_sigma, nlm_main).
//   (b) phase C rewritten with v_dot2_f32_f16 + v_perm packing: weights are
//       already packed half2 in swt; pixel pairs pack with 1 v_perm each.
//       8 fdot2 + 7 perm replaces 16 cvt + 16 fma + 3 add per row-task
//       (~64 VALU/iter saved; loop is VALU-issue-bound at 72%).
// R13: swt own buffer -> 3 barriers/iter, C overlaps next A. (unchanged)
// ----------------------------------------------------------------------------

#define IMG   1024
#define HH_S  257
#define NBINS 4096
#define NREP  2
#define BIN_SCALE 4096.0f
#define MED_K 33025      // n=257*257=66049 odd: median = a[33024] (0-based)
#define HITEMS (HH_S * HH_S * 3)     // 198147 per-channel HH items
#define HB 194                       // 194 blocks x 1024 = 198656 threads

#define TW 64
#define TH 32
// spx: rows -8..39 (48) x cols -14..77 (92)
#define PROWS 48
#define PCOLS 92
#define NPIX (PROWS*PCOLS)           // 4416
#define PXB(r,c) (((r)+8)*PCOLS + ((c)+14))
// sd: rows -8..33 (42) x cols -8..71 (80)
#define DCOLS 80
#define ND 3360                      // 42*80
// sh: rows -8..33 (42) x cols -6..69 (76)
#define HCOLS 76
#define NH 3192                      // 42*76
// swt: rows -6..31 (38) x cols -6..69 (76) — separate buffer (R13)
#define NW 2888                      // 38*76
#define NWP 1444                     // 38 rows x 38 col-pairs
#define SWB(r,c) (((r)+6)*HCOLS + ((c)+6))

// Gaussian patch kernel, normalized separable taps
#define G0 0.05448868454910367f
#define G1 0.24420134203151178f
#define G2 0.40261994689466440f
// horizontal pass taps pre-multiplied by 1/3 (channel mean)
#define B0 0.01816289484970122f
#define B1 0.08140044734383726f
#define B2 0.13420664896488813f

#define MAD_INV 1.4826022185056018f
#define LOG2E   1.4426950408889634f

typedef _Float16 half2v __attribute__((ext_vector_type(2)));
union PxU { uint2 u; half2v h[2]; };
union Q4  { uint4 u; half2v h[4]; };
union Q2  { uint2 u; half2v h[2]; };
#define H2(x) half2v{(_Float16)(x), (_Float16)(x)}

// ---------------------------------------------------------------- helpers
__device__ __forceinline__ float diff2(half2v a01, half2v a2, half2v b01, half2v b2) {
#if __has_builtin(__builtin_amdgcn_fdot2)
    half2v e01 = a01 - b01;
    half2v e2  = a2  - b2;
    return __builtin_amdgcn_fdot2(e01, e01,
           __builtin_amdgcn_fdot2(e2, e2, 0.f, false), false);
#else
    float e0 = (float)a01[0] - (float)b01[0];
    float e1 = (float)a01[1] - (float)b01[1];
    float e2 = (float)a2[0]  - (float)b2[0];
    return e0 * e0 + e1 * e1 + e2 * e2;
#endif
}

__device__ __forceinline__ float dot2(half2v a, half2v b, float c) {
#if __has_builtin(__builtin_amdgcn_fdot2)
    return __builtin_amdgcn_fdot2(a, b, c, false);
#else
    return c + (float)a[0] * (float)b[0] + (float)a[1] * (float)b[1];
#endif
}

__device__ __forceinline__ half2v pack2(float a, float b) {
#if __has_builtin(__builtin_amdgcn_cvt_pkrtz)
    return __builtin_bit_cast(half2v, __builtin_amdgcn_cvt_pkrtz(a, b));
#else
    return half2v{(_Float16)a, (_Float16)b};
#endif
}

// pack (lo16(A), lo16(B)) / (hi16(A), hi16(B)) / (lo16(A), hi16(B)) as half2
__device__ __forceinline__ half2v pklo(unsigned A, unsigned B) {
#if __has_builtin(__builtin_amdgcn_perm)
    return __builtin_bit_cast(half2v, __builtin_amdgcn_perm(B, A, 0x05040100u));
#else
    return __builtin_bit_cast(half2v, (A & 0xffffu) | (B << 16));
#endif
}
__device__ __forceinline__ half2v pkhi(unsigned A, unsigned B) {
#if __has_builtin(__builtin_amdgcn_perm)
    return __builtin_bit_cast(half2v, __builtin_amdgcn_perm(B, A, 0x07060302u));
#else
    return __builtin_bit_cast(half2v, (A >> 16) | (B & 0xffff0000u));
#endif
}
__device__ __forceinline__ half2v pklh(unsigned A, unsigned B) {
#if __has_builtin(__builtin_amdgcn_perm)
    return __builtin_bit_cast(half2v, __builtin_amdgcn_perm(B, A, 0x07060100u));
#else
    return __builtin_bit_cast(half2v, (A & 0xffffu) | (B & 0xffff0000u));
#endif
}

// load reflect-padded pixel tile, pack RGB -> 3xfp16 in uint2
__device__ __forceinline__ void tile_load(const float* __restrict__ x, uint2* spx,
                                          int tid, int X0, int Y0) {
    for (int l = tid; l < NPIX; l += 512) {
        int rr = l / PCOLS;
        int cc = l - rr * PCOLS;
        int sy = Y0 + rr - 8;
        sy = sy < 0 ? -sy : (sy >= IMG ? 2 * IMG - 2 - sy : sy);
        int sc = X0 + cc - 14;
        sc = sc < 0 ? -sc : (sc >= IMG ? 2 * IMG - 2 - sc : sc);
        const float* p = x + ((size_t)sy * IMG + sc) * 3;
        uint2 u;
        u.x = (unsigned)__half_as_ushort(__float2half_rn(p[0])) |
              ((unsigned)__half_as_ushort(__float2half_rn(p[1])) << 16);
        u.y = (unsigned)__half_as_ushort(__float2half_rn(p[2]));  // hi 16 = 0
        spx[l] = u;
    }
}

// one HH coefficient for one channel -> histogram atomic (stride-2 SAMPLED
// grid; numerically verified in R14)
__device__ __forceinline__ void hist_accum(const float* __restrict__ x,
                                           int* __restrict__ hist,
                                           int gtid, int rep) {
    if (gtid >= HITEMS) return;
    int idx = gtid / 3;
    int c   = gtid - idx * 3;
    int i = idx / HH_S;
    int j = idx - i * HH_S;
    const float k4[4] = {-0.48296291314469025f, 0.8365163037378079f,
                         -0.2241438680420134f, -0.12940952255126037f};
    float acc = 0.f;
    const bool fast = (j >= 2);          // j <= 256 so upper bound always ok
#pragma unroll
    for (int a = 0; a < 4; ++a) {
        int sy = 2 * i + a - 3;                       // 'symmetric' pad
        sy = sy < 0 ? -sy - 1 : (sy >= IMG ? 2 * IMG - 1 - sy : sy);
        const float* row = x + (size_t)sy * IMG * 3;
        float r;
        if (fast) {
            const float* p = row + (2 * j - 3) * 3 + c;
            r = k4[0] * p[0] + k4[1] * p[3] + k4[2] * p[6] + k4[3] * p[9];
        } else {
            r = 0.f;
#pragma unroll
            for (int b = 0; b < 4; ++b) {
                int sx = 2 * j + b - 3;
                sx = sx < 0 ? -sx - 1 : sx;
                r += k4[b] * row[sx * 3 + c];
            }
        }
        acc += k4[a] * r;
    }
    int b0 = (int)(fabsf(acc) * BIN_SCALE); b0 = b0 > NBINS - 1 ? NBINS - 1 : b0;
    atomicAdd(&hist[rep * 3 * NBINS + c * NBINS + b0], 1);
}

// ---------------------------------------------------------------- stage 1+2
// hist atomics from all blocks; LAST block (atomic-counter rendezvous,
// standard threadfence-reduction pattern) runs the 3-channel median scan
// and writes the final sigma scale to scal[0].
__global__ __launch_bounds__(1024)
void hist_sigma(const float* __restrict__ x, int* __restrict__ hist,
                float* __restrict__ scal, int* __restrict__ done) {
    const int t = threadIdx.x;
    hist_accum(x, hist, blockIdx.x * 1024 + t, blockIdx.x & (NREP - 1));

    __threadfence();                     // publish hist atomics (agent scope)
    __shared__ int islast;
    if (t == 0) islast = (atomicAdd(done, 1) == HB - 1);
    __syncthreads();
    if (!islast) return;
    __threadfence();                     // acquire side

    __shared__ int   wsum[16];
    __shared__ float sres;
    const int lane = t & 63, wid = t >> 6;
    float sig = 0.f;
#pragma unroll 1
    for (int ch = 0; ch < 3; ++ch) {
        const int* h = hist + ch * NBINS;
        int cnt[4]; int tsum = 0;
#pragma unroll
        for (int b = 0; b < 4; ++b) {
            int bin = t * 4 + b;
            int s = __hip_atomic_load(&h[bin], __ATOMIC_RELAXED, __HIP_MEMORY_SCOPE_AGENT)
                  + __hip_atomic_load(&h[3 * NBINS + bin], __ATOMIC_RELAXED, __HIP_MEMORY_SCOPE_AGENT);
            cnt[b] = s; tsum += s;
        }
        int incl = tsum;
#pragma unroll
        for (int o = 1; o < 64; o <<= 1) {
            int v = __shfl_up(incl, o);
            if (lane >= o) incl += v;
        }
        if (lane == 63) wsum[wid] = incl;
        __syncthreads();
        if (wid == 0) {
            int v = (lane < 16) ? wsum[lane] : 0;
            int inc = v;
#pragma unroll
            for (int o = 1; o < 16; o <<= 1) {
                int u = __shfl_up(inc, o);
                if (lane >= o) inc += u;
            }
            if (lane < 16) wsum[lane] = inc - v;
        }
        __syncthreads();
        int cum = wsum[wid] + incl - tsum;
#pragma unroll
        for (int b = 0; b < 4; ++b) {
            int nc = cum + cnt[b];
            if (cum < MED_K && nc >= MED_K)
                sres = (t * 4 + b + 0.5f) * (1.0f / BIN_SCALE);
            cum = nc;
        }
        __syncthreads();
        sig += sres;
        // wsum/sres reuse across channels is barrier-safe: next write to
        // either happens only after every thread passed the barrier above.
    }
    if (t == 0) scal[0] = sig * (MAD_INV / 3.0f);
}

// ---------------------------------------------------------------- main loop
// R13 structure: 42 iters x (A: packed diff^2 -> sds, B: horiz 5-tap -> shh,
// W: vert 5-tap + exp2 -> swt, C: fdot2 accumulate). 3 barriers/iter.
__device__ __forceinline__ void nlm_loop(float* __restrict__ out, float sigma,
                                         uint2* spx, half2v* sds, half2v* shh,
                                         half2v* swt, int tid, int X0, int Y0) {
    const float var   = 2.0f * sigma * sigma;
    const float ih2l  = LOG2E / (0.64f * sigma * sigma);   // h = 0.8*sigma

    const int c  = tid & 63;          // output col within tile
    const int rg = (tid >> 6) * 4;    // first of 4 output rows (0..28)
    float accx[4] = {0, 0, 0, 0}, accy[4] = {0, 0, 0, 0};
    float accz[4] = {0, 0, 0, 0}, accw[4] = {0, 0, 0, 0};

    __syncthreads();

    // --- register-cache center values + spx base index for phase A tasks
    half2v ctr01[7], ctr2[7];
    int    pb[7];
#pragma unroll
    for (int k = 0; k < 7; ++k) {
        int i = (k < 6 || tid < ND - 6 * 512) ? tid + k * 512 : 0;
        int dr = i / DCOLS;
        int dc = i - dr * DCOLS;
        pb[k] = dr * PCOLS + dc + 6;   // PXB(dr-8, dc-8)
        PxU p; p.u = spx[pb[k]];
        ctr01[k] = p.h[0]; ctr2[k] = p.h[1];
    }

    const half2v B0h = H2(B0), B1h = H2(B1), B2h = H2(B2);
    const half2v G0h = H2(G0), G1h = H2(G1), G2h = H2(G2);
    const half2v ones = H2(1.0f);

    // ---- pair body: offsets o1=(oy1,ox1), o2=(oy2,ox2) packed as half2;
    // each serves BOTH +o and -o directions (dist_{-o}(p) = dist_o(p-o)).
    auto pair_body = [&](auto mtag, int oy1, int ox1, int oy2, int ox2) {
        constexpr bool MERGED = decltype(mtag)::value;
        const int d1off = oy1 * PCOLS + ox1;
        const int d2off = oy2 * PCOLS + ox2;

        // -------- phase A: packed diff^2 on 42x80 ext region -> sds
#pragma unroll
        for (int k = 0; k < 7; ++k) {
            if (k < 6 || tid < ND - 6 * 512) {
                PxU p1, p2;
                p1.u = spx[pb[k] + d1off];
                if constexpr (MERGED) p2.u = spx[pb[k] + d1off + 1];
                else                  p2.u = spx[pb[k] + d2off];
                float da = diff2(ctr01[k], ctr2[k], p1.h[0], p1.h[1]);
                float db = diff2(ctr01[k], ctr2[k], p2.h[0], p2.h[1]);
                sds[tid + k * 512] = pack2(da, db);
            }
        }
        __syncthreads();

        // -------- phase B: packed horizontal conv -> shh (798 b128 tasks)
        {
            int row = tid / 19, g = tid - row * 19;
            int b = row * DCOLS + 4 * g;
            Q4 a, q, o;
            a.u = *(const uint4*)&sds[b];
            q.u = *(const uint4*)&sds[b + 4];
            o.h[0] = B0h * a.h[0] + B1h * a.h[1] + B2h * a.h[2] + B1h * a.h[3] + B0h * q.h[0];
            o.h[1] = B0h * a.h[1] + B1h * a.h[2] + B2h * a.h[3] + B1h * q.h[0] + B0h * q.h[1];
            o.h[2] = B0h * a.h[2] + B1h * a.h[3] + B2h * q.h[0] + B1h * q.h[1] + B0h * q.h[2];
            o.h[3] = B0h * a.h[3] + B1h * q.h[0] + B2h * q.h[1] + B1h * q.h[2] + B0h * q.h[3];
            *(uint4*)&shh[row * HCOLS + 4 * g] = o.u;
            if (tid < 798 - 512) {
                int j2 = tid + 512;
                int row2 = j2 / 19, g2 = j2 - row2 * 19;
                int b2 = row2 * DCOLS + 4 * g2;
                a.u = *(const uint4*)&sds[b2];
                q.u = *(const uint4*)&sds[b2 + 4];
                o.h[0] = B0h * a.h[0] + B1h * a.h[1] + B2h * a.h[2] + B1h * a.h[3] + B0h * q.h[0];
                o.h[1] = B0h * a.h[1] + B1h * a.h[2] + B2h * a.h[3] + B1h * q.h[0] + B0h * q.h[1];
                o.h[2] = B0h * a.h[2] + B1h * a.h[3] + B2h * q.h[0] + B1h * q.h[1] + B0h * q.h[2];
                o.h[3] = B0h * a.h[3] + B1h * q.h[0] + B2h * q.h[1] + B1h * q.h[2] + B0h * q.h[3];
                *(uint4*)&shh[row2 * HCOLS + 4 * g2] = o.u;
            }
        }
        __syncthreads();

        // -------- phase W: vert conv + exp2 weights, column-pair b64 tasks
#pragma unroll
        for (int k = 0; k < 3; ++k) {
            int t = tid + k * 512;
            if (k < 2 || t < NWP) {
                int row = t / 38, cp = t - row * 38;
                int m = row * HCOLS + 2 * cp;
                Q2 s0, s1, s2, s3, s4, o;
                s0.u = *(const uint2*)&shh[m];
                s1.u = *(const uint2*)&shh[m + HCOLS];
                s2.u = *(const uint2*)&shh[m + 2 * HCOLS];
                s3.u = *(const uint2*)&shh[m + 3 * HCOLS];
                s4.u = *(const uint2*)&shh[m + 4 * HCOLS];
                half2v d0 = G0h * s0.h[0] + G1h * s1.h[0] + G2h * s2.h[0] + G1h * s3.h[0] + G0h * s4.h[0];
                half2v d1 = G0h * s0.h[1] + G1h * s1.h[1] + G2h * s2.h[1] + G1h * s3.h[1] + G0h * s4.h[1];
                o.h[0] = pack2(exp2f(fminf(var - (float)d0[0], 0.f) * ih2l),
                               exp2f(fminf(var - (float)d0[1], 0.f) * ih2l));
                o.h[1] = pack2(exp2f(fminf(var - (float)d1[0], 0.f) * ih2l),
                               exp2f(fminf(var - (float)d1[1], 0.f) * ih2l));
                *(uint2*)&swt[m] = o.u;
            }
        }
        __syncthreads();

        // -------- phase C: accumulate 4 directions per packed pair via
        // v_dot2_f32_f16 (weights already packed; pixel pairs packed by perm).
        // (overlaps with next iteration's phase A — no trailing barrier)
#pragma unroll
        for (int j = 0; j < 4; ++j) {
            int r = rg + j;
            half2v wp = swt[SWB(r, c)];               // (w1, w2)
            unsigned u1, u2;
            PxU pa, pbx, pm1, pm2;
            if constexpr (MERGED) {
                int wmb = SWB(r - oy1, c - ox1);
                u1 = *(const unsigned*)&swt[wmb];
                u2 = *(const unsigned*)&swt[wmb - 1];
                int ab = PXB(r + oy1, c + ox1);
                pa.u  = spx[ab]; pbx.u = spx[ab + 1];
                int mb = PXB(r - oy1, c - ox1);
                pm1.u = spx[mb]; pm2.u = spx[mb - 1];
            } else {
                u1 = *(const unsigned*)&swt[SWB(r - oy1, c - ox1)];
                u2 = *(const unsigned*)&swt[SWB(r - oy2, c - ox2)];
                pa.u  = spx[PXB(r + oy1, c + ox1)];
                pbx.u = spx[PXB(r + oy2, c + ox2)];
                pm1.u = spx[PXB(r - oy1, c - ox1)];
                pm2.u = spx[PXB(r - oy2, c - ox2)];
            }
            half2v fm = pklh(u1, u2);                 // (f1, f2)
            accx[j] = dot2(fm, pklo(pm1.u.x, pm2.u.x),
                      dot2(wp, pklo(pa.u.x, pbx.u.x), accx[j]));
            accy[j] = dot2(fm, pkhi(pm1.u.x, pm2.u.x),
                      dot2(wp, pkhi(pa.u.x, pbx.u.x), accy[j]));
            accz[j] = dot2(fm, pklo(pm1.u.y, pm2.u.y),
                      dot2(wp, pklo(pa.u.y, pbx.u.y), accz[j]));
            accw[j] = dot2(fm, ones, dot2(wp, ones, accw[j]));
        }
    };

    // ---- 42 iterations cover 84 representative offsets x 2 directions:
    // oy=0: ox 1..6 as merged pairs (1,2),(3,4),(5,6)
#pragma unroll 1
    for (int pi = 0; pi < 3; ++pi)
        pair_body(std::integral_constant<bool, true>{}, 0, 1 + 2 * pi, 0, 2 + 2 * pi);
    // oy=1..6: ox -6..5 as 6 merged pairs per row
#pragma unroll 1
    for (int oy = 1; oy <= 6; ++oy)
#pragma unroll 1
        for (int pi = 0; pi < 6; ++pi)
            pair_body(std::integral_constant<bool, true>{}, oy, -6 + 2 * pi, oy, -5 + 2 * pi);
    // leftovers (oy,6) for oy=1..6 as 3 generic pairs
#pragma unroll 1
    for (int p = 0; p < 3; ++p)
        pair_body(std::integral_constant<bool, false>{}, 2 * p + 1, 6, 2 * p + 2, 6);

    // -------- offset (0,0): d=0 -> w=1
#pragma unroll
    for (int j = 0; j < 4; ++j) {
        PxU p; p.u = spx[PXB(rg + j, c)];
        accx[j] += (float)p.h[0][0];
        accy[j] += (float)p.h[0][1];
        accz[j] += (float)p.h[1][0];
        accw[j] += 1.f;
    }

    // -------- epilogue
#pragma unroll
    for (int j = 0; j < 4; ++j) {
        int po = ((Y0 + rg + j) * IMG + X0 + c) * 3;
        float rw = 1.f / accw[j];
        out[po + 0] = accx[j] * rw;
        out[po + 1] = accy[j] * rw;
        out[po + 2] = accz[j] * rw;
    }
}

// ---------------------------------------------------------------- stage 3
__launch_bounds__(512, 4)
__global__ void nlm_main(const float* __restrict__ x,
                         const float* __restrict__ scal,
                         float* __restrict__ out) {
    __shared__ __align__(16) uint2  spx[NPIX];   // packed half RGB (RO in loop)
    __shared__ __align__(16) half2v sds[ND];     // diff^2 pairs
    __shared__ __align__(16) half2v shh[NH];     // horiz-conv pairs
    __shared__ __align__(16) half2v swt[NW];     // weight pairs

    const int tid = threadIdx.x;
    const int X0 = blockIdx.x * TW;
    const int Y0 = blockIdx.y * TH;

    tile_load(x, spx, tid, X0, Y0);
    const float sigma = scal[0];
    nlm_loop(out, sigma, spx, sds, shh, swt, tid, X0, Y0);
}

// ---------------------------------------------------------------- launch
extern "C" void kernel_launch(void* const* d_in, const int* in_sizes, int n_in,
                              void* d_out, int out_size, void* d_ws, size_t ws_size,
                              hipStream_t stream) {
    const float* x = (const float*)d_in[0];
    float* out = (float*)d_out;
    float* scal = (float*)d_ws;                       // [0] = final sigma scale
    int* done = (int*)d_ws + 4;                       // byte 16: block counter
    int* hist = (int*)((char*)d_ws + 64);             // NREP x 3 x 4096 ints

    // zero scal + done + histograms in one memset
    (void)hipMemsetAsync(d_ws, 0, 64 + NREP * 3 * NBINS * sizeof(int), stream);

    hist_sigma<<<HB, 1024, 0, stream>>>(x, hist, scal, done);
    dim3 grid(IMG / TW, IMG / TH);
    nlm_main<<<grid, 512, 0, stream>>>(x, scal, out);
}